// Round 1
// baseline (725.645 us; speedup 1.0000x reference)
//
#include <hip/hip_runtime.h>

#define B_    64
#define T_    256
#define TA_   255
#define OBS_  512
#define ACT_  32
#define LAT_  64
#define NB_   8
#define BS_   8
#define PHI_  512
#define BT_   16384
#define BTA_  16320

// output layout (floats): latent | rho | predicted_latents | predicted_obs
#define RHO_OFF   1048576ULL
#define PL_OFF    67895296ULL
#define POBS_OFF  68943872ULL

__device__ const float HC_[6] = {1.f/120.f, 1.f/24.f, 1.f/6.f, 0.5f, 1.f, 1.f};

// ---------------- encoder: latent = obs @ W_enc + b_enc ----------------
// block = 256 (4 waves); each wave: 8 rows x 64 cols. lane = col.
__global__ __launch_bounds__(256) void enc_kernel(
    const float* __restrict__ obs, const float* __restrict__ W,
    const float* __restrict__ bias, float* __restrict__ latent)
{
    const int wave = threadIdx.x >> 6;
    const int lane = threadIdx.x & 63;
    const int row0 = (blockIdx.x * 4 + wave) * 8;
    float bv = bias[lane];
    float acc[8];
#pragma unroll
    for (int g = 0; g < 8; ++g) acc[g] = bv;
    const float* op = obs + (size_t)row0 * OBS_;
    for (int a = 0; a < OBS_; a += 4) {
        float w0 = W[(a + 0) * LAT_ + lane];
        float w1 = W[(a + 1) * LAT_ + lane];
        float w2 = W[(a + 2) * LAT_ + lane];
        float w3 = W[(a + 3) * LAT_ + lane];
#pragma unroll
        for (int g = 0; g < 8; ++g) {
            float4 o = *(const float4*)(op + (size_t)g * OBS_ + a);
            acc[g] = fmaf(o.x, w0, acc[g]);
            acc[g] = fmaf(o.y, w1, acc[g]);
            acc[g] = fmaf(o.z, w2, acc[g]);
            acc[g] = fmaf(o.w, w3, acc[g]);
        }
    }
#pragma unroll
    for (int g = 0; g < 8; ++g)
        latent[(size_t)(row0 + g) * LAT_ + lane] = acc[g];
}

// ---------------- 8x8 matmul in registers ----------------
__device__ __forceinline__ void mm8(float* __restrict__ D,
                                    const float* __restrict__ X,
                                    const float* __restrict__ Y)
{
#pragma unroll
    for (int r = 0; r < 8; ++r)
#pragma unroll
        for (int c = 0; c < 8; ++c) {
            float s = 0.f;
#pragma unroll
            for (int q = 0; q < 8; ++q) s = fmaf(X[r * 8 + q], Y[q * 8 + c], s);
            D[r * 8 + c] = s;
        }
}

// ---------------- phi GEMM + expm, one 8x8 block per thread ----------------
// grid = (ceil(BTA/256), 8); blockIdx.y = k  (wave-uniform -> W_phi loads are scalar)
__global__ __launch_bounds__(256, 2) void phi_expm_kernel(
    const float* __restrict__ act, const float* __restrict__ Wp,
    const float* __restrict__ bp, float* __restrict__ out_blocks,
    float* __restrict__ rho, int use_ws)
{
    const int bt = blockIdx.x * 256 + threadIdx.x;
    const int k  = blockIdx.y;
    if (bt >= BTA_) return;

    float ph[64];
    {
        const float* bpp = bp + k * 64;
#pragma unroll
        for (int p = 0; p < 64; ++p) ph[p] = bpp[p];
    }
    const float* arow = act + (size_t)bt * ACT_;
    const float* wk = Wp + k * 64;
#pragma unroll 2
    for (int a = 0; a < ACT_; ++a) {
        float av = arow[a];
        const float* wr = wk + (size_t)a * PHI_;
#pragma unroll
        for (int p = 0; p < 64; ++p) ph[p] = fmaf(av, wr[p], ph[p]);
    }

    // M[r][c] = ph[c*8+r] (reference transposes each block); A = M / 8
    float A[64];
#pragma unroll
    for (int r = 0; r < 8; ++r)
#pragma unroll
        for (int c = 0; c < 8; ++c) A[r * 8 + c] = 0.125f * ph[c * 8 + r];

    // degree-7 Taylor, Horner: P = (A/7! ) + I/6! then 6x (P = A*P + c I)
    float P[64], Tt[64];
#pragma unroll
    for (int i = 0; i < 64; ++i) P[i] = (1.f / 5040.f) * A[i];
#pragma unroll
    for (int d = 0; d < 8; ++d) P[d * 9] += 1.f / 720.f;

    for (int it = 0; it < 3; ++it) {
        mm8(Tt, A, P);
        float c0 = HC_[2 * it];
#pragma unroll
        for (int d = 0; d < 8; ++d) Tt[d * 9] += c0;
        mm8(P, A, Tt);
        float c1 = HC_[2 * it + 1];
#pragma unroll
        for (int d = 0; d < 8; ++d) P[d * 9] += c1;
    }
    // 3 squarings: E = P^(2^3)
    for (int sq = 0; sq < 3; ++sq) {
        mm8(Tt, P, P);
#pragma unroll
        for (int i = 0; i < 64; ++i) P[i] = Tt[i];
    }

    if (use_ws) {
        float* dst = out_blocks + ((size_t)bt * NB_ + k) * 64;
#pragma unroll
        for (int i = 0; i < 16; ++i)
            ((float4*)dst)[i] = make_float4(P[4*i], P[4*i+1], P[4*i+2], P[4*i+3]);
    } else {
        float* base = rho + ((size_t)bt * LAT_ + k * BS_) * LAT_ + k * BS_;
#pragma unroll
        for (int r = 0; r < 8; ++r) {
            *(float4*)(base + (size_t)r * LAT_)     = make_float4(P[r*8+0], P[r*8+1], P[r*8+2], P[r*8+3]);
            *(float4*)(base + (size_t)r * LAT_ + 4) = make_float4(P[r*8+4], P[r*8+5], P[r*8+6], P[r*8+7]);
        }
    }
}

// ---------------- rho writer: zeros + block diagonal, fully coalesced ----------------
__global__ __launch_bounds__(256) void rho_write_kernel(
    const float* __restrict__ blocks, float* __restrict__ rho)
{
    size_t idx = (size_t)blockIdx.x * 256 + threadIdx.x;   // float4 index
    int c4 = (int)(idx & 15);
    size_t rowg = idx >> 4;
    int row = (int)(rowg & 63);
    size_t bt = rowg >> 6;
    int k = row >> 3, r = row & 7;
    float4 v = make_float4(0.f, 0.f, 0.f, 0.f);
    if ((c4 >> 1) == k)
        v = ((const float4*)(blocks + ((bt * 8 + (size_t)k) * 64 + (size_t)r * 8)))[c4 & 1];
    ((float4*)rho)[idx] = v;
}

__global__ __launch_bounds__(256) void zero_kernel(float4* __restrict__ p)
{
    p[(size_t)blockIdx.x * 256 + threadIdx.x] = make_float4(0.f, 0.f, 0.f, 0.f);
}

// ---------------- recurrence: 512 independent (b,k) chains ----------------
__device__ __forceinline__ void load_block8(float* __restrict__ dst,
                                            const float* __restrict__ p, int rs)
{
#pragma unroll
    for (int r = 0; r < 8; ++r) {
        float4 x = *(const float4*)(p + (size_t)r * rs);
        float4 y = *(const float4*)(p + (size_t)r * rs + 4);
        dst[r*8+0] = x.x; dst[r*8+1] = x.y; dst[r*8+2] = x.z; dst[r*8+3] = x.w;
        dst[r*8+4] = y.x; dst[r*8+5] = y.y; dst[r*8+6] = y.z; dst[r*8+7] = y.w;
    }
}

__global__ __launch_bounds__(64) void recur_kernel(
    const float* __restrict__ latent, const float* __restrict__ eb,
    int chainA, int chainB, int ts, int rs, float* __restrict__ pl)
{
    const int tid = blockIdx.x * 64 + threadIdx.x;   // 0..511
    const int b = tid >> 3, k = tid & 7;
    const float* e = eb + (size_t)b * (size_t)chainA + (size_t)k * (size_t)chainB;

    float h[8];
    const float* l0 = latent + (size_t)b * T_ * LAT_ + k * 8;
#pragma unroll
    for (int j = 0; j < 8; ++j) h[j] = l0[j];
    float* plp = pl + (size_t)b * T_ * LAT_ + k * 8;
    *(float4*)(plp)     = make_float4(h[0], h[1], h[2], h[3]);
    *(float4*)(plp + 4) = make_float4(h[4], h[5], h[6], h[7]);

    float eA[64], eB[64];
    load_block8(eA, e, rs);

#define STEP_(EBUF)                                                          \
    {                                                                        \
        float nh[8];                                                         \
        _Pragma("unroll")                                                    \
        for (int c = 0; c < 8; ++c) {                                        \
            float s = 0.f;                                                   \
            _Pragma("unroll")                                                \
            for (int r = 0; r < 8; ++r) s = fmaf(h[r], EBUF[r * 8 + c], s);  \
            nh[c] = s;                                                       \
        }                                                                    \
        plp += LAT_;                                                         \
        *(float4*)(plp)     = make_float4(nh[0], nh[1], nh[2], nh[3]);       \
        *(float4*)(plp + 4) = make_float4(nh[4], nh[5], nh[6], nh[7]);       \
        _Pragma("unroll")                                                    \
        for (int j = 0; j < 8; ++j) h[j] = nh[j];                            \
    }

    for (int t = 0; t < TA_; t += 2) {
        int tn = (t + 1 < TA_) ? t + 1 : TA_ - 1;
        load_block8(eB, e + (size_t)tn * ts, rs);      // prefetch t+1
        STEP_(eA);                                     // consume t
        if (t + 1 >= TA_) break;
        int tn2 = (t + 2 < TA_) ? t + 2 : TA_ - 1;
        load_block8(eA, e + (size_t)tn2 * ts, rs);     // prefetch t+2
        STEP_(eB);                                     // consume t+1
    }
#undef STEP_
}

// ---------------- decoder: pobs = pl @ W_dec + b_dec ----------------
// thread = (8-row group, 4-col group); lane-uniform pl -> scalar loads
__global__ __launch_bounds__(256) void dec_kernel(
    const float* __restrict__ pl, const float* __restrict__ W,
    const float* __restrict__ bias, float* __restrict__ out)
{
    const int gid = blockIdx.x * 256 + threadIdx.x;
    const int o4 = gid & 127;
    const int bt0 = (gid >> 7) * 8;
    float4 bv = ((const float4*)bias)[o4];
    float4 acc[8];
#pragma unroll
    for (int g = 0; g < 8; ++g) acc[g] = bv;
    const float4* wp = (const float4*)W;
#pragma unroll 2
    for (int l4 = 0; l4 < 16; ++l4) {
        float4 w0 = wp[(4 * l4 + 0) * 128 + o4];
        float4 w1 = wp[(4 * l4 + 1) * 128 + o4];
        float4 w2 = wp[(4 * l4 + 2) * 128 + o4];
        float4 w3 = wp[(4 * l4 + 3) * 128 + o4];
#pragma unroll
        for (int g = 0; g < 8; ++g) {
            float4 s = ((const float4*)(pl + (size_t)(bt0 + g) * LAT_))[l4];
            acc[g].x = fmaf(s.x, w0.x, acc[g].x); acc[g].y = fmaf(s.x, w0.y, acc[g].y);
            acc[g].z = fmaf(s.x, w0.z, acc[g].z); acc[g].w = fmaf(s.x, w0.w, acc[g].w);
            acc[g].x = fmaf(s.y, w1.x, acc[g].x); acc[g].y = fmaf(s.y, w1.y, acc[g].y);
            acc[g].z = fmaf(s.y, w1.z, acc[g].z); acc[g].w = fmaf(s.y, w1.w, acc[g].w);
            acc[g].x = fmaf(s.z, w2.x, acc[g].x); acc[g].y = fmaf(s.z, w2.y, acc[g].y);
            acc[g].z = fmaf(s.z, w2.z, acc[g].z); acc[g].w = fmaf(s.z, w2.w, acc[g].w);
            acc[g].x = fmaf(s.w, w3.x, acc[g].x); acc[g].y = fmaf(s.w, w3.y, acc[g].y);
            acc[g].z = fmaf(s.w, w3.z, acc[g].z); acc[g].w = fmaf(s.w, w3.w, acc[g].w);
        }
    }
#pragma unroll
    for (int g = 0; g < 8; ++g)
        ((float4*)out)[(size_t)(bt0 + g) * 128 + o4] = acc[g];
}

extern "C" void kernel_launch(void* const* d_in, const int* in_sizes, int n_in,
                              void* d_out, int out_size, void* d_ws, size_t ws_size,
                              hipStream_t stream)
{
    const float* obs  = (const float*)d_in[0];
    const float* act  = (const float*)d_in[1];
    const float* Wenc = (const float*)d_in[2];
    const float* benc = (const float*)d_in[3];
    const float* Wdec = (const float*)d_in[4];
    const float* bdec = (const float*)d_in[5];
    const float* Wphi = (const float*)d_in[6];
    const float* bphi = (const float*)d_in[7];

    float* out    = (float*)d_out;
    float* latent = out;
    float* rho    = out + RHO_OFF;
    float* pl     = out + PL_OFF;
    float* pobs   = out + POBS_OFF;

    const size_t need = (size_t)BTA_ * NB_ * 64 * sizeof(float);  // 33.4 MB
    const bool use_ws = (ws_size >= need);
    float* eb = (float*)d_ws;

    // 1) encoder (latent needed by recurrence for h0)
    hipLaunchKernelGGL(enc_kernel, dim3(BT_ / 32), dim3(256), 0, stream,
                       obs, Wenc, benc, latent);

    // 2) phi + expm
    if (!use_ws)
        hipLaunchKernelGGL(zero_kernel, dim3(66846720 / 1024), dim3(256), 0, stream,
                           (float4*)rho);
    hipLaunchKernelGGL(phi_expm_kernel, dim3((BTA_ + 255) / 256, NB_), dim3(256), 0, stream,
                       act, Wphi, bphi, eb, rho, (int)use_ws);

    // 3) recurrence over 255 steps (512 independent chains)
    if (use_ws)
        hipLaunchKernelGGL(recur_kernel, dim3(8), dim3(64), 0, stream,
                           latent, eb, TA_ * 512, 64, 512, 8, pl);
    else
        hipLaunchKernelGGL(recur_kernel, dim3(8), dim3(64), 0, stream,
                           latent, rho, TA_ * 4096, BS_ * LAT_ + BS_, 4096, LAT_, pl);

    // 4) rho materialization (zeros + diagonal blocks)
    if (use_ws)
        hipLaunchKernelGGL(rho_write_kernel, dim3(66846720 / 1024), dim3(256), 0, stream,
                           eb, rho);

    // 5) decoder
    hipLaunchKernelGGL(dec_kernel, dim3(BT_ / 8 * 128 / 256), dim3(256), 0, stream,
                       pl, Wdec, bdec, pobs);
}

// Round 2
// 698.467 us; speedup vs baseline: 1.0389x; 1.0389x over previous
//
#include <hip/hip_runtime.h>

#define B_    64
#define T_    256
#define TA_   255
#define OBS_  512
#define ACT_  32
#define LAT_  64
#define NB_   8
#define BS_   8
#define PHI_  512
#define BT_   16384
#define BTA_  16320
#define CH_   16
#define NCH_  16

// output layout (floats): latent | rho | predicted_latents | predicted_obs
#define RHO_OFF   1048576ULL
#define PL_OFF    67895296ULL
#define POBS_OFF  68943872ULL

__device__ const float HC_[6] = {1.f/120.f, 1.f/24.f, 1.f/6.f, 0.5f, 1.f, 1.f};

// ---------------- encoder: latent = obs @ W_enc + b_enc ----------------
// 64-thread blocks: obs row addresses derive from blockIdx only -> provably
// wave-uniform -> s_load_dwordx4 (scalar pipe), W loads stay vector/coalesced.
__global__ __launch_bounds__(64) void enc_kernel(
    const float* __restrict__ obs, const float* __restrict__ W,
    const float* __restrict__ bias, float* __restrict__ latent)
{
    const int lane = threadIdx.x;
    const int row0 = blockIdx.x * 8;
    float bv = bias[lane];
    float acc[8];
#pragma unroll
    for (int g = 0; g < 8; ++g) acc[g] = bv;
    const float* op = obs + (size_t)row0 * OBS_;
    for (int a = 0; a < OBS_; a += 4) {
        float w0 = W[(a + 0) * LAT_ + lane];
        float w1 = W[(a + 1) * LAT_ + lane];
        float w2 = W[(a + 2) * LAT_ + lane];
        float w3 = W[(a + 3) * LAT_ + lane];
#pragma unroll
        for (int g = 0; g < 8; ++g) {
            float4 o = *(const float4*)(op + (size_t)g * OBS_ + a);
            acc[g] = fmaf(o.x, w0, acc[g]);
            acc[g] = fmaf(o.y, w1, acc[g]);
            acc[g] = fmaf(o.z, w2, acc[g]);
            acc[g] = fmaf(o.w, w3, acc[g]);
        }
    }
#pragma unroll
    for (int g = 0; g < 8; ++g)
        latent[(size_t)(row0 + g) * LAT_ + lane] = acc[g];
}

// ---------------- 8x8 matmul in registers ----------------
__device__ __forceinline__ void mm8(float* __restrict__ D,
                                    const float* __restrict__ X,
                                    const float* __restrict__ Y)
{
#pragma unroll
    for (int r = 0; r < 8; ++r)
#pragma unroll
        for (int c = 0; c < 8; ++c) {
            float s = 0.f;
#pragma unroll
            for (int q = 0; q < 8; ++q) s = fmaf(X[r * 8 + q], Y[q * 8 + c], s);
            D[r * 8 + c] = s;
        }
}

// ---------------- phi GEMM + expm, one 8x8 block per thread ----------------
// launch_bounds(256,1): peak live state ~200 floats (A,P,Tt) -- the (256,2)
// 256-VGPR cap risked scratch spills; 512-VGPR budget removes them.
__global__ __launch_bounds__(256, 1) void phi_expm_kernel(
    const float* __restrict__ act, const float* __restrict__ Wp,
    const float* __restrict__ bp, float* __restrict__ out_blocks,
    float* __restrict__ rho, int use_ws)
{
    const int bt = blockIdx.x * 256 + threadIdx.x;
    const int k  = blockIdx.y;
    if (bt >= BTA_) return;

    float ph[64];
    {
        const float* bpp = bp + k * 64;
#pragma unroll
        for (int p = 0; p < 64; ++p) ph[p] = bpp[p];
    }
    const float* arow = act + (size_t)bt * ACT_;
    const float* wk = Wp + k * 64;
#pragma unroll 2
    for (int a = 0; a < ACT_; ++a) {
        float av = arow[a];
        const float* wr = wk + (size_t)a * PHI_;
#pragma unroll
        for (int p = 0; p < 64; ++p) ph[p] = fmaf(av, wr[p], ph[p]);
    }

    // M[r][c] = ph[c*8+r] (reference transposes each block); A = M / 8
    float A[64];
#pragma unroll
    for (int r = 0; r < 8; ++r)
#pragma unroll
        for (int c = 0; c < 8; ++c) A[r * 8 + c] = 0.125f * ph[c * 8 + r];

    // degree-7 Taylor, Horner: P = A/7! + I/6!; then 6x (P = A*P + c I)
    float P[64], Tt[64];
#pragma unroll
    for (int i = 0; i < 64; ++i) P[i] = (1.f / 5040.f) * A[i];
#pragma unroll
    for (int d = 0; d < 8; ++d) P[d * 9] += 1.f / 720.f;

    for (int it = 0; it < 3; ++it) {
        mm8(Tt, A, P);
        float c0 = HC_[2 * it];
#pragma unroll
        for (int d = 0; d < 8; ++d) Tt[d * 9] += c0;
        mm8(P, A, Tt);
        float c1 = HC_[2 * it + 1];
#pragma unroll
        for (int d = 0; d < 8; ++d) P[d * 9] += c1;
    }
    // 3 squarings: E = P^(2^3)
    for (int sq = 0; sq < 3; ++sq) {
        mm8(Tt, P, P);
#pragma unroll
        for (int i = 0; i < 64; ++i) P[i] = Tt[i];
    }

    if (use_ws) {
        float* dst = out_blocks + ((size_t)bt * NB_ + k) * 64;
#pragma unroll
        for (int i = 0; i < 16; ++i)
            ((float4*)dst)[i] = make_float4(P[4*i], P[4*i+1], P[4*i+2], P[4*i+3]);
    } else {
        float* base = rho + ((size_t)bt * LAT_ + k * BS_) * LAT_ + k * BS_;
#pragma unroll
        for (int r = 0; r < 8; ++r) {
            *(float4*)(base + (size_t)r * LAT_)     = make_float4(P[r*8+0], P[r*8+1], P[r*8+2], P[r*8+3]);
            *(float4*)(base + (size_t)r * LAT_ + 4) = make_float4(P[r*8+4], P[r*8+5], P[r*8+6], P[r*8+7]);
        }
    }
}

// ---------------- rho writer: zeros + block diagonal, fully coalesced ----------------
__global__ __launch_bounds__(256) void rho_write_kernel(
    const float* __restrict__ blocks, float* __restrict__ rho)
{
    size_t idx = (size_t)blockIdx.x * 256 + threadIdx.x;   // float4 index
    int c4 = (int)(idx & 15);
    size_t rowg = idx >> 4;
    int row = (int)(rowg & 63);
    size_t bt = rowg >> 6;
    int k = row >> 3, r = row & 7;
    float4 v = make_float4(0.f, 0.f, 0.f, 0.f);
    if ((c4 >> 1) == k)
        v = ((const float4*)(blocks + ((bt * 8 + (size_t)k) * 64 + (size_t)r * 8)))[c4 & 1];
    ((float4*)rho)[idx] = v;
}

__global__ __launch_bounds__(256) void zero_kernel(float4* __restrict__ p)
{
    p[(size_t)blockIdx.x * 256 + threadIdx.x] = make_float4(0.f, 0.f, 0.f, 0.f);
}

// ======== parallel scan over the recurrence h_{t+1} = h_t * M_t ========
// Phase A: per (b,k,chunk) local prefix products L_i = M_{t0}...M_{t0+i}
__global__ __launch_bounds__(256) void scan_local_kernel(
    const float* __restrict__ eb, float* __restrict__ pfx)
{
    const int tid = blockIdx.x * 256 + threadIdx.x;   // 8192 threads
    const int k = tid & 7;
    const int j = (tid >> 3) & 15;
    const int b = tid >> 7;
    const int t0 = j * CH_;
    const int cnt = (TA_ - t0 < CH_) ? (TA_ - t0) : CH_;   // 16 (15 for last)
    const float* src = eb  + ((size_t)(b * TA_ + t0) * 8 + k) * 64;
    float*       dst = pfx + ((size_t)(b * TA_ + t0) * 8 + k) * 64;

    float R[64];
#pragma unroll
    for (int q = 0; q < 16; ++q) ((float4*)R)[q] = ((const float4*)src)[q];
#pragma unroll
    for (int q = 0; q < 16; ++q) ((float4*)dst)[q] = ((const float4*)R)[q];

    for (int i = 1; i < cnt; ++i) {
        const float* mp = src + (size_t)i * 512;
        float M[64];
#pragma unroll
        for (int q = 0; q < 16; ++q) ((float4*)M)[q] = ((const float4*)mp)[q];
        // R = R * M, in place row-by-row (row r of output reads only row r of R)
#pragma unroll
        for (int r = 0; r < 8; ++r) {
            float tmp[8];
#pragma unroll
            for (int c = 0; c < 8; ++c) {
                float s = 0.f;
#pragma unroll
                for (int q = 0; q < 8; ++q) s = fmaf(R[r * 8 + q], M[q * 8 + c], s);
                tmp[c] = s;
            }
#pragma unroll
            for (int c = 0; c < 8; ++c) R[r * 8 + c] = tmp[c];
        }
        float* dp = dst + (size_t)i * 512;
#pragma unroll
        for (int q = 0; q < 16; ++q) ((float4*)dp)[q] = ((const float4*)R)[q];
    }
}

// Phase B: per (b,k) scan of chunk totals -> g_j = h0 * M_0..M_{16j-1}; pl[:,0]
__global__ __launch_bounds__(64) void scan_chunk_kernel(
    const float* __restrict__ latent, const float* __restrict__ pfx,
    float* __restrict__ gws, float* __restrict__ pl)
{
    const int tid = blockIdx.x * 64 + threadIdx.x;   // 512 threads
    const int k = tid & 7, b = tid >> 3;
    float g[8];
    const float* l0 = latent + (size_t)b * T_ * LAT_ + k * 8;
#pragma unroll
    for (int m = 0; m < 8; ++m) g[m] = l0[m];

    float* pl0 = pl + (size_t)b * T_ * LAT_ + k * 8;
    *(float4*)(pl0)     = make_float4(g[0], g[1], g[2], g[3]);
    *(float4*)(pl0 + 4) = make_float4(g[4], g[5], g[6], g[7]);

    float* gp = gws + ((size_t)(b * NCH_) * 8 + k) * 8;
    *(float4*)(gp)     = make_float4(g[0], g[1], g[2], g[3]);
    *(float4*)(gp + 4) = make_float4(g[4], g[5], g[6], g[7]);

    for (int j = 1; j < NCH_; ++j) {
        const float* cp = pfx + ((size_t)(b * TA_ + j * CH_ - 1) * 8 + k) * 64;
        float C[64];
#pragma unroll
        for (int q = 0; q < 16; ++q) ((float4*)C)[q] = ((const float4*)cp)[q];
        float ng[8];
#pragma unroll
        for (int m = 0; m < 8; ++m) {
            float s = 0.f;
#pragma unroll
            for (int l = 0; l < 8; ++l) s = fmaf(g[l], C[l * 8 + m], s);
            ng[m] = s;
        }
#pragma unroll
        for (int m = 0; m < 8; ++m) g[m] = ng[m];
        float* gq = gws + ((size_t)(b * NCH_ + j) * 8 + k) * 8;
        *(float4*)(gq)     = make_float4(g[0], g[1], g[2], g[3]);
        *(float4*)(gq + 4) = make_float4(g[4], g[5], g[6], g[7]);
    }
}

// Phase C: per (b,t,k): h_t = g_j * L_{j,i}  -> pl[b,t+1,k*8..]
__global__ __launch_bounds__(256) void scan_emit_kernel(
    const float* __restrict__ pfx, const float* __restrict__ gws,
    float* __restrict__ pl)
{
    const int tid = blockIdx.x * 256 + threadIdx.x;   // 130560 threads
    const int k = tid & 7;
    const int bt = tid >> 3;            // 0..16319
    const int b = bt / TA_;
    const int t = bt - b * TA_;
    const int j = t >> 4;               // CH_ = 16

    float g[8];
    const float* gp = gws + ((size_t)(b * NCH_ + j) * 8 + k) * 8;
    *(float4*)(g)     = *(const float4*)(gp);
    *(float4*)(g + 4) = *(const float4*)(gp + 4);

    const float* lp = pfx + ((size_t)bt * 8 + k) * 64;
    float L[64];
#pragma unroll
    for (int q = 0; q < 16; ++q) ((float4*)L)[q] = ((const float4*)lp)[q];

    float h[8];
#pragma unroll
    for (int m = 0; m < 8; ++m) {
        float s = 0.f;
#pragma unroll
        for (int l = 0; l < 8; ++l) s = fmaf(g[l], L[l * 8 + m], s);
        h[m] = s;
    }
    float* op = pl + ((size_t)b * T_ + t + 1) * LAT_ + k * 8;
    *(float4*)(op)     = make_float4(h[0], h[1], h[2], h[3]);
    *(float4*)(op + 4) = make_float4(h[4], h[5], h[6], h[7]);
}

// ---------------- sequential recurrence (fallback for small ws) ----------------
__device__ __forceinline__ void load_block8(float* __restrict__ dst,
                                            const float* __restrict__ p, int rs)
{
#pragma unroll
    for (int r = 0; r < 8; ++r) {
        float4 x = *(const float4*)(p + (size_t)r * rs);
        float4 y = *(const float4*)(p + (size_t)r * rs + 4);
        dst[r*8+0] = x.x; dst[r*8+1] = x.y; dst[r*8+2] = x.z; dst[r*8+3] = x.w;
        dst[r*8+4] = y.x; dst[r*8+5] = y.y; dst[r*8+6] = y.z; dst[r*8+7] = y.w;
    }
}

__global__ __launch_bounds__(64) void recur_kernel(
    const float* __restrict__ latent, const float* __restrict__ eb,
    int chainA, int chainB, int ts, int rs, float* __restrict__ pl)
{
    const int tid = blockIdx.x * 64 + threadIdx.x;   // 0..511
    const int b = tid >> 3, k = tid & 7;
    const float* e = eb + (size_t)b * (size_t)chainA + (size_t)k * (size_t)chainB;

    float h[8];
    const float* l0 = latent + (size_t)b * T_ * LAT_ + k * 8;
#pragma unroll
    for (int j = 0; j < 8; ++j) h[j] = l0[j];
    float* plp = pl + (size_t)b * T_ * LAT_ + k * 8;
    *(float4*)(plp)     = make_float4(h[0], h[1], h[2], h[3]);
    *(float4*)(plp + 4) = make_float4(h[4], h[5], h[6], h[7]);

    float eA[64], eB[64];
    load_block8(eA, e, rs);

#define STEP_(EBUF)                                                          \
    {                                                                        \
        float nh[8];                                                         \
        _Pragma("unroll")                                                    \
        for (int c = 0; c < 8; ++c) {                                        \
            float s = 0.f;                                                   \
            _Pragma("unroll")                                                \
            for (int r = 0; r < 8; ++r) s = fmaf(h[r], EBUF[r * 8 + c], s);  \
            nh[c] = s;                                                       \
        }                                                                    \
        plp += LAT_;                                                         \
        *(float4*)(plp)     = make_float4(nh[0], nh[1], nh[2], nh[3]);       \
        *(float4*)(plp + 4) = make_float4(nh[4], nh[5], nh[6], nh[7]);       \
        _Pragma("unroll")                                                    \
        for (int j = 0; j < 8; ++j) h[j] = nh[j];                            \
    }

    for (int t = 0; t < TA_; t += 2) {
        int tn = (t + 1 < TA_) ? t + 1 : TA_ - 1;
        load_block8(eB, e + (size_t)tn * ts, rs);
        STEP_(eA);
        if (t + 1 >= TA_) break;
        int tn2 = (t + 2 < TA_) ? t + 2 : TA_ - 1;
        load_block8(eA, e + (size_t)tn2 * ts, rs);
        STEP_(eB);
    }
#undef STEP_
}

// ---------------- decoder: pobs = pl @ W_dec + b_dec ----------------
__global__ __launch_bounds__(256) void dec_kernel(
    const float* __restrict__ pl, const float* __restrict__ W,
    const float* __restrict__ bias, float* __restrict__ out)
{
    const int gid = blockIdx.x * 256 + threadIdx.x;
    const int o4 = gid & 127;
    const int bt0 = (gid >> 7) * 8;
    float4 bv = ((const float4*)bias)[o4];
    float4 acc[8];
#pragma unroll
    for (int g = 0; g < 8; ++g) acc[g] = bv;
    const float4* wp = (const float4*)W;
#pragma unroll 2
    for (int l4 = 0; l4 < 16; ++l4) {
        float4 w0 = wp[(4 * l4 + 0) * 128 + o4];
        float4 w1 = wp[(4 * l4 + 1) * 128 + o4];
        float4 w2 = wp[(4 * l4 + 2) * 128 + o4];
        float4 w3 = wp[(4 * l4 + 3) * 128 + o4];
#pragma unroll
        for (int g = 0; g < 8; ++g) {
            float4 s = ((const float4*)(pl + (size_t)(bt0 + g) * LAT_))[l4];
            acc[g].x = fmaf(s.x, w0.x, acc[g].x); acc[g].y = fmaf(s.x, w0.y, acc[g].y);
            acc[g].z = fmaf(s.x, w0.z, acc[g].z); acc[g].w = fmaf(s.x, w0.w, acc[g].w);
            acc[g].x = fmaf(s.y, w1.x, acc[g].x); acc[g].y = fmaf(s.y, w1.y, acc[g].y);
            acc[g].z = fmaf(s.y, w1.z, acc[g].z); acc[g].w = fmaf(s.y, w1.w, acc[g].w);
            acc[g].x = fmaf(s.z, w2.x, acc[g].x); acc[g].y = fmaf(s.z, w2.y, acc[g].y);
            acc[g].z = fmaf(s.z, w2.z, acc[g].z); acc[g].w = fmaf(s.z, w2.w, acc[g].w);
            acc[g].x = fmaf(s.w, w3.x, acc[g].x); acc[g].y = fmaf(s.w, w3.y, acc[g].y);
            acc[g].z = fmaf(s.w, w3.z, acc[g].z); acc[g].w = fmaf(s.w, w3.w, acc[g].w);
        }
    }
#pragma unroll
    for (int g = 0; g < 8; ++g)
        ((float4*)out)[(size_t)(bt0 + g) * 128 + o4] = acc[g];
}

extern "C" void kernel_launch(void* const* d_in, const int* in_sizes, int n_in,
                              void* d_out, int out_size, void* d_ws, size_t ws_size,
                              hipStream_t stream)
{
    const float* obs  = (const float*)d_in[0];
    const float* act  = (const float*)d_in[1];
    const float* Wenc = (const float*)d_in[2];
    const float* benc = (const float*)d_in[3];
    const float* Wdec = (const float*)d_in[4];
    const float* bdec = (const float*)d_in[5];
    const float* Wphi = (const float*)d_in[6];
    const float* bphi = (const float*)d_in[7];

    float* out    = (float*)d_out;
    float* latent = out;
    float* rho    = out + RHO_OFF;
    float* pl     = out + PL_OFF;
    float* pobs   = out + POBS_OFF;

    const size_t eb_elems = (size_t)BTA_ * NB_ * 64;          // 8,355,840 floats
    const size_t need_ws   = eb_elems * sizeof(float);         // 33.4 MB
    const size_t need_scan = (2 * eb_elems + 512 * NCH_ * 8) * sizeof(float);  // 64 MB
    const bool use_ws   = (ws_size >= need_ws);
    const bool use_scan = (ws_size >= need_scan);
    float* eb  = (float*)d_ws;
    float* pfx = eb + eb_elems;
    float* gws = pfx + eb_elems;

    // 1) encoder
    hipLaunchKernelGGL(enc_kernel, dim3(BT_ / 8), dim3(64), 0, stream,
                       obs, Wenc, benc, latent);

    // 2) phi + expm
    if (!use_ws)
        hipLaunchKernelGGL(zero_kernel, dim3(66846720 / 1024), dim3(256), 0, stream,
                           (float4*)rho);
    hipLaunchKernelGGL(phi_expm_kernel, dim3((BTA_ + 255) / 256, NB_), dim3(256), 0, stream,
                       act, Wphi, bphi, eb, rho, (int)use_ws);

    // 3) recurrence
    if (use_scan) {
        hipLaunchKernelGGL(scan_local_kernel, dim3(8192 / 256), dim3(256), 0, stream,
                           eb, pfx);
        hipLaunchKernelGGL(scan_chunk_kernel, dim3(8), dim3(64), 0, stream,
                           latent, pfx, gws, pl);
        hipLaunchKernelGGL(scan_emit_kernel, dim3(BTA_ * NB_ / 256), dim3(256), 0, stream,
                           pfx, gws, pl);
    } else if (use_ws) {
        hipLaunchKernelGGL(recur_kernel, dim3(8), dim3(64), 0, stream,
                           latent, eb, TA_ * 512, 64, 512, 8, pl);
    } else {
        hipLaunchKernelGGL(recur_kernel, dim3(8), dim3(64), 0, stream,
                           latent, rho, TA_ * 4096, BS_ * LAT_ + BS_, 4096, LAT_, pl);
    }

    // 4) rho materialization (zeros + diagonal blocks)
    if (use_ws)
        hipLaunchKernelGGL(rho_write_kernel, dim3(66846720 / 1024), dim3(256), 0, stream,
                           eb, rho);

    // 5) decoder
    hipLaunchKernelGGL(dec_kernel, dim3(BT_ / 8 * 128 / 256), dim3(256), 0, stream,
                       pl, Wdec, bdec, pobs);
}